// Round 4
// baseline (179.002 us; speedup 1.0000x reference)
//
#include <hip/hip_runtime.h>

#define HW_   5776   // 76*76
#define W_    76
#define NC_   80     // classes
#define NA_   3      // anchors
#define NB_   16     // batch
#define NPOS  (NB_ * NA_ * HW_)   // 277248 total positions
#define ROWQ  24     // padded float4 slots per LDS position row (xor swizzle)

__device__ __forceinline__ float sigmoidf_(float x) {
    return 1.0f / (1.0f + __expf(-x));
}

// Lane-pair (lane, lane^32) covers 2 consecutive positions with float2 loads:
// half 0 handles classes 0..39, half 1 classes 40..79; softmax max/sum joined
// via __shfl_xor(.,32). Conf output staged through a per-wave 16-position LDS
// buffer (4 passes, reused -- wave DS ops are in program order, no barrier)
// and drained as fully coalesced float4 stores.
__global__ __launch_bounds__(128, 4) void yolo_kernel(const float* __restrict__ in,
                                                      float* __restrict__ out) {
    __shared__ float4 lds[2][16 * ROWQ];   // 6 KB per wave, 12 KB per block

    const int tid  = threadIdx.x;
    const int lane = tid & 63;
    const int wv   = tid >> 6;            // wave in block (0..1)
    const int half = lane >> 5;           // 0 or 1
    const int pair = lane & 31;           // lane-pair index

    const int waveP0 = blockIdx.x * 128 + wv * 64;  // first position of wave
    const int P0     = waveP0 + pair * 2;           // this thread's positions P0, P0+1

    const int slab = P0 / HW_;            // b*3 + a; P0 even, HW_ even => P0+1 same slab
    const int p    = P0 - slab * HW_;
    const int a    = slab % NA_;

    const float aw3[3] = {1.5f, 2.375f, 5.0f};   // [12,19,40]/8
    const float ah3[3] = {2.0f, 4.5f, 3.5f};     // [16,36,28]/8
    const float invW = 1.0f / 76.0f;

    const float* src = in + (size_t)slab * (85 * (size_t)HW_) + p;   // 8B aligned

    // box channels 0..4 as float2 (both halves same addresses -> merged)
    const float2 b0 = *(const float2*)(src + 0 * (size_t)HW_);
    const float2 b1 = *(const float2*)(src + 1 * (size_t)HW_);
    const float2 b2 = *(const float2*)(src + 2 * (size_t)HW_);
    const float2 b3 = *(const float2*)(src + 3 * (size_t)HW_);
    const float2 b4 = *(const float2*)(src + 4 * (size_t)HW_);

    // this half's 40 class channels, 2 positions each
    const float* csrc = src + (size_t)(5 + half * 40) * HW_;
    float2 v[40];
#pragma unroll
    for (int c = 0; c < 40; ++c) v[c] = *(const float2*)(csrc + (size_t)c * HW_);

    // grid coords for p and p+1 (p+1 may wrap a row)
    const int x0 = p % W_;
    const int y0 = p / W_;
    const int wrap = (x0 == W_ - 1);
    const int x1 = wrap ? 0 : x0 + 1;
    const int y1 = y0 + wrap;

    const float bx0 = (sigmoidf_(b0.x) + (float)x0) * invW;
    const float by0 = (sigmoidf_(b1.x) + (float)y0) * invW;
    const float bw0 = __expf(b2.x) * (aw3[a] * invW);
    const float bh0 = __expf(b3.x) * (ah3[a] * invW);
    const float d0  = sigmoidf_(b4.x);
    const float bx1 = (sigmoidf_(b0.y) + (float)x1) * invW;
    const float by1 = (sigmoidf_(b1.y) + (float)y1) * invW;
    const float bw1 = __expf(b2.y) * (aw3[a] * invW);
    const float bh1 = __expf(b3.y) * (ah3[a] * invW);
    const float d1  = sigmoidf_(b4.y);

    // softmax over 80 classes, split 40/40 across the lane pair, 2 positions
    float m0 = v[0].x, m1 = v[0].y;
#pragma unroll
    for (int c = 1; c < 40; ++c) { m0 = fmaxf(m0, v[c].x); m1 = fmaxf(m1, v[c].y); }
    m0 = fmaxf(m0, __shfl_xor(m0, 32));
    m1 = fmaxf(m1, __shfl_xor(m1, 32));
    float s0 = 0.0f, s1 = 0.0f;
#pragma unroll
    for (int c = 0; c < 40; ++c) {
        v[c].x = __expf(v[c].x - m0); s0 += v[c].x;
        v[c].y = __expf(v[c].y - m1); s1 += v[c].y;
    }
    s0 += __shfl_xor(s0, 32);
    s1 += __shfl_xor(s1, 32);
    const float sc0 = d0 / s0;
    const float sc1 = d1 / s1;

    // boxes: [B][A*HW][4]; lanes of half 0 write 2 consecutive float4 each
    if (half == 0) {
        float4* out4 = (float4*)out;
        out4[P0]     = make_float4(bx0, by0, bw0, bh0);
        out4[P0 + 1] = make_float4(bx1, by1, bw1, bh1);
    }

    // conf: [B][A*HW][NC] after boxes; 4 passes of 16 positions through LDS
    float4* conf4 = (float4*)out + NPOS + (size_t)waveP0 * 20;
    const int myt = pair >> 3;            // pass in which this thread stages
    const int lp0 = (pair & 7) * 2;       // local position of q=0 within pass
#pragma unroll
    for (int t = 0; t < 4; ++t) {
        if (myt == t) {
#pragma unroll
            for (int i = 0; i < 10; ++i) {
                const int k = half * 10 + i;
                const int sl0 = lp0 * ROWQ + (k ^ (lp0 & 7));
                lds[wv][sl0] = make_float4(v[4*i].x * sc0, v[4*i+1].x * sc0,
                                           v[4*i+2].x * sc0, v[4*i+3].x * sc0);
                const int lp1 = lp0 + 1;
                const int sl1 = lp1 * ROWQ + (k ^ (lp1 & 7));
                lds[wv][sl1] = make_float4(v[4*i].y * sc1, v[4*i+1].y * sc1,
                                           v[4*i+2].y * sc1, v[4*i+3].y * sc1);
            }
        }
        // drain 16 positions = 320 float4, fully coalesced
#pragma unroll
        for (int i = 0; i < 5; ++i) {
            const int f    = i * 64 + lane;        // 0..319
            const int lp   = f / 20;
            const int kq   = f - lp * 20;
            const int slot = lp * ROWQ + (kq ^ (lp & 7));
            conf4[t * 320 + f] = lds[wv][slot];
        }
    }
}

extern "C" void kernel_launch(void* const* d_in, const int* in_sizes, int n_in,
                              void* d_out, int out_size, void* d_ws, size_t ws_size,
                              hipStream_t stream) {
    const float* in = (const float*)d_in[0];
    float* out = (float*)d_out;
    const int nblocks = NPOS / 128;   // 2166, exact (128 positions per block)
    yolo_kernel<<<nblocks, 128, 0, stream>>>(in, out);
}

// Round 5
// 167.924 us; speedup vs baseline: 1.0660x; 1.0660x over previous
//
#include <hip/hip_runtime.h>

#define HW_   5776   // 76*76
#define W_    76
#define NC_   80     // classes
#define NA_   3      // anchors
#define NB_   16     // batch
#define NPOS  (NB_ * NA_ * HW_)   // 277248 total positions
#define ROWQ  24     // padded float4 slots per LDS position row (xor swizzle room)

__device__ __forceinline__ float sigmoidf_(float x) {
    return 1.0f / (1.0f + __expf(-x));
}

// R3 structure (2 lanes per position, scalar dword loads, 68 VGPR, no spill)
// with conf staging shrunk to a 6 KB per-wave buffer reused over 2 passes of
// 16 positions each. Wave DS ops execute in program order -> stage/drain/stage
// /drain on the same buffer needs no barrier. LDS 24 KB/block -> 6 blocks/CU
// -> 24-wave occupancy cap (2x R3).
__global__ __launch_bounds__(256) void yolo_kernel(const float* __restrict__ in,
                                                   float* __restrict__ out) {
    __shared__ float4 lds[4][16 * ROWQ];   // 6 KB per wave, 24 KB per block

    const int tid   = threadIdx.x;
    const int lane  = tid & 63;
    const int wv    = tid >> 6;           // wave within block (0..3)
    const int half  = lane >> 5;          // 0 or 1 (class split)
    const int pair  = lane & 31;          // wave-local position index
    const int Pbase = blockIdx.x * 128 + wv * 32;  // first position of this wave
    const int P     = Pbase + pair;

    const int slab = P / HW_;             // = b*3 + a   (0..47)
    const int p    = P - slab * HW_;      // position in 76x76 plane
    const int a    = slab % NA_;

    const float aw3[3] = {1.5f, 2.375f, 5.0f};   // [12,19,40]/8
    const float ah3[3] = {2.0f, 4.5f, 3.5f};     // [16,36,28]/8
    const float invW = 1.0f / 76.0f;

    const float* src = in + (size_t)slab * (85 * (size_t)HW_) + p;

    // box channels 0..4 (same addresses across halves -> coalescer-merged)
    const float b0 = src[0 * (size_t)HW_];
    const float b1 = src[1 * (size_t)HW_];
    const float b2 = src[2 * (size_t)HW_];
    const float b3 = src[3 * (size_t)HW_];
    const float b4 = src[4 * (size_t)HW_];

    // this half's 40 class channels
    const float* csrc = src + (size_t)(5 + half * 40) * HW_;
    float v[40];
#pragma unroll
    for (int c = 0; c < 40; ++c) v[c] = csrc[(size_t)c * HW_];

    const int x = p % W_;
    const int y = p / W_;
    const float bx  = (sigmoidf_(b0) + (float)x) * invW;
    const float by  = (sigmoidf_(b1) + (float)y) * invW;
    const float bw  = __expf(b2) * (aw3[a] * invW);
    const float bh  = __expf(b3) * (ah3[a] * invW);
    const float det = sigmoidf_(b4);

    // softmax across 80 classes, split 40/40 over the lane pair
    float m = v[0];
#pragma unroll
    for (int c = 1; c < 40; ++c) m = fmaxf(m, v[c]);
    m = fmaxf(m, __shfl_xor(m, 32));
    float s = 0.0f;
#pragma unroll
    for (int c = 0; c < 40; ++c) { v[c] = __expf(v[c] - m); s += v[c]; }
    s += __shfl_xor(s, 32);
    const float scale = det / s;

    // boxes: [B][A*HW][4]; row index == P; coalesced 512B per half-wave
    if (half == 0) {
        ((float4*)out)[P] = make_float4(bx, by, bw, bh);
    }

    // ---- conf via 2-pass per-wave LDS transpose ----
    // pass t stages positions Pbase + t*16 .. +15 (pairs with pair>>4 == t),
    // then the whole wave drains 320 float4 fully coalesced.
    float4* conf4 = (float4*)out + NPOS + (size_t)Pbase * 20;
    const int myt = pair >> 4;            // which pass this thread stages in
    const int lp  = pair & 15;            // local position within its pass
#pragma unroll
    for (int t = 0; t < 2; ++t) {
        if (myt == t) {
#pragma unroll
            for (int i = 0; i < 10; ++i) {
                const int k    = half * 10 + i;
                const int slot = lp * ROWQ + (k ^ (lp & 7));
                lds[wv][slot] = make_float4(v[4*i]   * scale, v[4*i+1] * scale,
                                            v[4*i+2] * scale, v[4*i+3] * scale);
            }
        }
        // drain 16 positions = 320 float4 (wave DS pipe is in program order)
#pragma unroll
        for (int i = 0; i < 5; ++i) {
            const int f    = i * 64 + lane;        // 0..319
            const int lpr  = f / 20;
            const int kq   = f - lpr * 20;
            const int slot = lpr * ROWQ + (kq ^ (lpr & 7));
            conf4[t * 320 + f] = lds[wv][slot];
        }
    }
}

extern "C" void kernel_launch(void* const* d_in, const int* in_sizes, int n_in,
                              void* d_out, int out_size, void* d_ws, size_t ws_size,
                              hipStream_t stream) {
    const float* in = (const float*)d_in[0];
    float* out = (float*)d_out;
    const int nblocks = NPOS / 128;   // 2166, exact (128 positions per block)
    yolo_kernel<<<nblocks, 256, 0, stream>>>(in, out);
}